// Round 1
// baseline (73.721 us; speedup 1.0000x reference)
//
#include <hip/hip_runtime.h>

// Fused tanh-RNN (T=64, I=64, H=100) + tanh + linear (C=40) for B=16384.
// One wave = 16 batch rows for all 64 timesteps. f16 MFMA 16x16x32.
// W_ih / W_hh fragments register-resident; h state round-trips through
// wave-private LDS (stride 264B: 2-way write conflicts (free), b64 reads clean).

typedef _Float16 half8 __attribute__((ext_vector_type(8)));
typedef _Float16 half4_t __attribute__((ext_vector_type(4)));
typedef float float4_t __attribute__((ext_vector_type(4)));

#define LDSROW 132  // _Float16 elements per row (128 data + 4 pad) -> 264B stride

__device__ __forceinline__ float tanh_fast(float x) {
  // tanh(x) = 1 - 2/(exp2(x*2*log2(e)) + 1); exact at +-inf, ~1e-7 rel err
  float e = __builtin_amdgcn_exp2f(x * 2.8853900817779268f);
  return 1.0f - 2.0f * __builtin_amdgcn_rcpf(e + 1.0f);
}

__global__ __launch_bounds__(256, 1) void rnn_fused(
    const float* __restrict__ x, const float* __restrict__ W_ih,
    const float* __restrict__ W_hh, const float* __restrict__ b_ih,
    const float* __restrict__ b_hh, const float* __restrict__ fc_W,
    const float* __restrict__ fc_b, float* __restrict__ out, int B)
{
  __shared__ _Float16 lds[4][16 * LDSROW];
  const int lane = threadIdx.x & 63;
  const int wave = threadIdx.x >> 6;
  const int g = lane >> 4;   // k-group within fragment (0..3)
  const int c = lane & 15;   // col-in-tile (B frag / D) == row (A frag)
  _Float16* h_lds = lds[wave];

  const int rowbase = (blockIdx.x * 4 + wave) * 16;
  if (rowbase >= B) return;

  // ---- zero wave-private h state (padding cols 100..131 stay 0 forever)
  {
    int* p = (int*)h_lds;
    #pragma unroll
    for (int i = 0; i < 17; ++i) {
      int idx = lane + i * 64;
      if (idx < 16 * LDSROW / 2) p[idx] = 0;
    }
  }

  // ---- load weight fragments into registers
  // B-frag (16x16x32): lane holds B[k = 32*kb + 8*g + j][n = 16*nt + c], j=0..7
  half8 wih[2][7];    // W_ih^T: B[i][n] = W_ih[n][i], K=64
  half8 whh[4][7];    // W_hh^T: B[k][n] = W_hh[n][k], K=100 padded to 128
  float4_t biasv[7];  // b_ih[n] + b_hh[n], splat over 4 acc rows
  #pragma unroll
  for (int nt = 0; nt < 7; ++nt) {
    int n = nt * 16 + c;
    bool nv = (n < 100);
    float bb = nv ? (b_ih[n] + b_hh[n]) : 0.0f;
    biasv[nt] = (float4_t){bb, bb, bb, bb};
    #pragma unroll
    for (int kb = 0; kb < 2; ++kb) {
      float4_t f0 = {0,0,0,0}, f1 = {0,0,0,0};
      if (nv) {
        const float* p = W_ih + n * 64 + kb * 32 + g * 8;
        f0 = *(const float4_t*)p;
        f1 = *(const float4_t*)(p + 4);
      }
      half8 h;
      #pragma unroll
      for (int j = 0; j < 4; ++j) { h[j] = (_Float16)f0[j]; h[4+j] = (_Float16)f1[j]; }
      wih[kb][nt] = h;
    }
    #pragma unroll
    for (int kb = 0; kb < 4; ++kb) {
      int k = kb * 32 + g * 8;
      float4_t f0 = {0,0,0,0}, f1 = {0,0,0,0};
      if (nv && k < 100) {
        const float* p = W_hh + n * 100 + k;
        f0 = *(const float4_t*)p;            // k<=96: first 4 always valid
        if (k <= 92) f1 = *(const float4_t*)(p + 4);  // k==96 -> only 96..99 valid
      }
      half8 h;
      #pragma unroll
      for (int j = 0; j < 4; ++j) { h[j] = (_Float16)f0[j]; h[4+j] = (_Float16)f1[j]; }
      whh[kb][nt] = h;
    }
  }

  // ---- x streaming: lane reads row (rowbase+c), 16 floats/step at k=8g(+32)
  const float* xrow = x + (size_t)(rowbase + c) * 4096;
  float4_t s0, s1, s2, s3;
  {
    const float* p = xrow + g * 8;
    s0 = *(const float4_t*)p;        s1 = *(const float4_t*)(p + 4);
    s2 = *(const float4_t*)(p + 32); s3 = *(const float4_t*)(p + 36);
  }

  float4_t acc[7];

  for (int t = 0; t < 64; ++t) {
    // prefetch next step's x
    float4_t n0 = {0,0,0,0}, n1 = {0,0,0,0}, n2 = {0,0,0,0}, n3 = {0,0,0,0};
    if (t < 63) {
      const float* p = xrow + (t + 1) * 64 + g * 8;
      n0 = *(const float4_t*)p;        n1 = *(const float4_t*)(p + 4);
      n2 = *(const float4_t*)(p + 32); n3 = *(const float4_t*)(p + 36);
    }

    // x A-frags (f16)
    half8 xa0, xa1;
    #pragma unroll
    for (int j = 0; j < 4; ++j) {
      xa0[j]   = (_Float16)s0[j]; xa0[4+j] = (_Float16)s1[j];
      xa1[j]   = (_Float16)s2[j]; xa1[4+j] = (_Float16)s3[j];
    }

    // input projection: acc = bias + x_t @ W_ih^T
    #pragma unroll
    for (int nt = 0; nt < 7; ++nt) {
      acc[nt] = __builtin_amdgcn_mfma_f32_16x16x32_f16(xa0, wih[0][nt], biasv[nt], 0, 0, 0);
      acc[nt] = __builtin_amdgcn_mfma_f32_16x16x32_f16(xa1, wih[1][nt], acc[nt], 0, 0, 0);
    }

    // recurrence: acc += h_{t} @ W_hh^T   (h_lds holds h from prev step; zeros at t=0)
    #pragma unroll
    for (int kb = 0; kb < 4; ++kb) {
      half4_t lo = *(const half4_t*)&h_lds[c * LDSROW + kb * 32 + g * 8];
      half4_t hi = *(const half4_t*)&h_lds[c * LDSROW + kb * 32 + g * 8 + 4];
      half8 ha;
      #pragma unroll
      for (int j = 0; j < 4; ++j) { ha[j] = lo[j]; ha[4+j] = hi[j]; }
      #pragma unroll
      for (int nt = 0; nt < 7; ++nt)
        acc[nt] = __builtin_amdgcn_mfma_f32_16x16x32_f16(ha, whh[kb][nt], acc[nt], 0, 0, 0);
    }

    // h_{t+1} = tanh(acc); write back to LDS (D-layout -> [row][k] A source)
    #pragma unroll
    for (int nt = 0; nt < 7; ++nt) {
      #pragma unroll
      for (int v = 0; v < 4; ++v) {
        float th = tanh_fast(acc[nt][v]);
        acc[nt][v] = th;  // keep last h in regs for epilogue
        if (nt < 6 || c < 4)  // only cols < 100
          h_lds[(g * 4 + v) * LDSROW + nt * 16 + c] = (_Float16)th;
      }
    }

    s0 = n0; s1 = n1; s2 = n2; s3 = n3;
  }

  // ---- epilogue: out = tanh(h_last) @ fc_W^T + fc_b
  // second tanh, rewrite into LDS as fc-GEMM A source
  #pragma unroll
  for (int nt = 0; nt < 7; ++nt) {
    #pragma unroll
    for (int v = 0; v < 4; ++v) {
      float th2 = tanh_fast(acc[nt][v]);
      if (nt < 6 || c < 4)
        h_lds[(g * 4 + v) * LDSROW + nt * 16 + c] = (_Float16)th2;
    }
  }

  half8 wfc[4][3];
  float4_t bfc[3];
  #pragma unroll
  for (int nt = 0; nt < 3; ++nt) {
    int n = nt * 16 + c;
    bool nv = (n < 40);
    float bb = nv ? fc_b[n] : 0.0f;
    bfc[nt] = (float4_t){bb, bb, bb, bb};
    #pragma unroll
    for (int kb = 0; kb < 4; ++kb) {
      int k = kb * 32 + g * 8;
      float4_t f0 = {0,0,0,0}, f1 = {0,0,0,0};
      if (nv && k < 100) {
        const float* p = fc_W + n * 100 + k;
        f0 = *(const float4_t*)p;
        if (k <= 92) f1 = *(const float4_t*)(p + 4);
      }
      half8 h;
      #pragma unroll
      for (int j = 0; j < 4; ++j) { h[j] = (_Float16)f0[j]; h[4+j] = (_Float16)f1[j]; }
      wfc[kb][nt] = h;
    }
  }

  float4_t oacc[3];
  #pragma unroll
  for (int kb = 0; kb < 4; ++kb) {
    half4_t lo = *(const half4_t*)&h_lds[c * LDSROW + kb * 32 + g * 8];
    half4_t hi = *(const half4_t*)&h_lds[c * LDSROW + kb * 32 + g * 8 + 4];
    half8 ha;
    #pragma unroll
    for (int j = 0; j < 4; ++j) { ha[j] = lo[j]; ha[4+j] = hi[j]; }
    #pragma unroll
    for (int nt = 0; nt < 3; ++nt)
      oacc[nt] = __builtin_amdgcn_mfma_f32_16x16x32_f16(
          ha, wfc[kb][nt], (kb == 0) ? bfc[nt] : oacc[nt], 0, 0, 0);
  }

  #pragma unroll
  for (int nt = 0; nt < 3; ++nt) {
    #pragma unroll
    for (int v = 0; v < 4; ++v) {
      int n = nt * 16 + c;
      if (n < 40) {
        int r = rowbase + g * 4 + v;
        out[(size_t)r * 40 + n] = oacc[nt][v];
      }
    }
  }
}

extern "C" void kernel_launch(void* const* d_in, const int* in_sizes, int n_in,
                              void* d_out, int out_size, void* d_ws, size_t ws_size,
                              hipStream_t stream) {
  const float* x    = (const float*)d_in[0];
  const float* W_ih = (const float*)d_in[1];
  const float* W_hh = (const float*)d_in[2];
  const float* b_ih = (const float*)d_in[3];
  const float* b_hh = (const float*)d_in[4];
  const float* fc_W = (const float*)d_in[5];
  const float* fc_b = (const float*)d_in[6];
  float* outp = (float*)d_out;

  int B = in_sizes[0] / 4096;      // 16384
  int grid = (B + 63) / 64;        // 64 rows per 4-wave block
  rnn_fused<<<grid, 256, 0, stream>>>(x, W_ih, W_hh, b_ih, b_hh, fc_W, fc_b, outp, B);
}

// Round 2
// 68.476 us; speedup vs baseline: 1.0766x; 1.0766x over previous
//
#include <hip/hip_runtime.h>

// Fused tanh-RNN (T=64, I=64, H=100) + tanh + linear (C=40), B=16384.
// TRANSPOSED formulation: D = A*B with A = weight fragments (register-resident),
// B = data^T (x / h). W_hh columns are pre-permuted by
//   phi(32kb+8g+e) = 32kb + 16*(e>>2) + 4g + (e&3)
// so the MFMA D-output registers ARE the next step's B-fragment after a
// per-lane f16 convert: no LDS, no cross-lane traffic, no barriers.
// One wave owns 16 batch rows for all 64 steps; 1024 waves = 1 wave/SIMD.

typedef _Float16 half8 __attribute__((ext_vector_type(8)));
typedef float float4_t __attribute__((ext_vector_type(4)));

__device__ __forceinline__ float tanh_fast(float x) {
  // tanh(x) = 1 - 2/(exp2(2x*log2e)+1); exact at +-inf
  float e = __builtin_amdgcn_exp2f(x * 2.8853900817779268f);
  return 1.0f - 2.0f * __builtin_amdgcn_rcpf(e + 1.0f);
}

__global__ __launch_bounds__(256, 1) void rnn_fused(
    const float* __restrict__ x, const float* __restrict__ W_ih,
    const float* __restrict__ W_hh, const float* __restrict__ b_ih,
    const float* __restrict__ b_hh, const float* __restrict__ fc_W,
    const float* __restrict__ fc_b, float* __restrict__ out, int B)
{
  const int lane = threadIdx.x & 63;
  const int wave = threadIdx.x >> 6;
  const int g = lane >> 4;   // k-group / D-row group
  const int c = lane & 15;   // batch col (B,D) == weight row (A)
  const int rowbase = (blockIdx.x * 4 + wave) * 16;

  // ---- A-fragment weights, register-resident.
  // A-frag (16x16x32): lane (g,c) element e holds A[m=c][k=8g+e].
  half8 wih[2][7];    // W_ih[16nt+c][32kb+8g+e]           (k = input dim, no perm)
  half8 whh[4][7];    // W_hh[16nt+c][phi(32kb+8g+e)]      (k = h dim, permuted)
  float4_t bias[7];   // (b_ih+b_hh)[16nt+4g+v]            (matches D layout)

  #pragma unroll
  for (int nt = 0; nt < 7; ++nt) {
    int nb = nt * 16 + 4 * g;
    float4_t bi = {0.f, 0.f, 0.f, 0.f};
    if (nb + 3 < 100) {
      float4_t a = *(const float4_t*)(b_ih + nb);
      float4_t b = *(const float4_t*)(b_hh + nb);
      bi = a + b;
    }
    bias[nt] = bi;

    int nrow = nt * 16 + c;
    bool rv = (nrow < 100);
    #pragma unroll
    for (int kb = 0; kb < 2; ++kb) {
      float4_t f0 = {0.f,0.f,0.f,0.f}, f1 = {0.f,0.f,0.f,0.f};
      if (rv) {
        const float* p = W_ih + nrow * 64 + kb * 32 + g * 8;
        f0 = *(const float4_t*)p;
        f1 = *(const float4_t*)(p + 4);
      }
      half8 h;
      #pragma unroll
      for (int j = 0; j < 4; ++j) { h[j] = (_Float16)f0[j]; h[4 + j] = (_Float16)f1[j]; }
      wih[kb][nt] = h;
    }
    #pragma unroll
    for (int kb = 0; kb < 4; ++kb) {
      // phi: elements 0..3 -> cols 32kb+4g+0..3 ; elements 4..7 -> cols 32kb+16+4g+0..3
      int clo = kb * 32 + 4 * g;
      int chi = clo + 16;
      float4_t f0 = {0.f,0.f,0.f,0.f}, f1 = {0.f,0.f,0.f,0.f};
      if (rv && clo + 3 < 100) f0 = *(const float4_t*)(W_hh + nrow * 100 + clo);
      if (rv && chi + 3 < 100) f1 = *(const float4_t*)(W_hh + nrow * 100 + chi);
      half8 h;
      #pragma unroll
      for (int j = 0; j < 4; ++j) { h[j] = (_Float16)f0[j]; h[4 + j] = (_Float16)f1[j]; }
      whh[kb][nt] = h;
    }
  }

  // ---- x streaming: lane (g,c) reads batch row (rowbase+c),
  // per step 16 floats at k = 8g..8g+7 and 32+8g..32+8g+7  (= x B-fragment).
  const float* xrow = x + (size_t)(rowbase + c) * 4096 + g * 8;
  float4_t s0, s1, s2, s3;   // x_t
  float4_t p0, p1, p2, p3;   // x_{t+1}
  {
    const float* p = xrow;
    s0 = *(const float4_t*)p;        s1 = *(const float4_t*)(p + 4);
    s2 = *(const float4_t*)(p + 32); s3 = *(const float4_t*)(p + 36);
    p += 64;
    p0 = *(const float4_t*)p;        p1 = *(const float4_t*)(p + 4);
    p2 = *(const float4_t*)(p + 32); p3 = *(const float4_t*)(p + 36);
  }

  float4_t acc[7];
  half8 hfrag[4];
  #pragma unroll
  for (int kb = 0; kb < 4; ++kb) hfrag[kb] = (half8)(_Float16)0.0f;  // h_0 = 0

  for (int t = 0; t < 64; ++t) {
    // prefetch x_{t+2}
    float4_t q0 = {0.f,0.f,0.f,0.f}, q1 = q0, q2 = q0, q3 = q0;
    if (t < 62) {
      const float* p = xrow + (t + 2) * 64;
      q0 = *(const float4_t*)p;        q1 = *(const float4_t*)(p + 4);
      q2 = *(const float4_t*)(p + 32); q3 = *(const float4_t*)(p + 36);
    }

    // x B-frags (f16)
    half8 xb0, xb1;
    #pragma unroll
    for (int j = 0; j < 4; ++j) {
      xb0[j] = (_Float16)s0[j]; xb0[4 + j] = (_Float16)s1[j];
      xb1[j] = (_Float16)s2[j]; xb1[4 + j] = (_Float16)s3[j];
    }

    // preact = bias + W_ih x_t^T + W_hh h_t^T
    #pragma unroll
    for (int nt = 0; nt < 7; ++nt) {
      acc[nt] = __builtin_amdgcn_mfma_f32_16x16x32_f16(wih[0][nt], xb0, bias[nt], 0, 0, 0);
      acc[nt] = __builtin_amdgcn_mfma_f32_16x16x32_f16(wih[1][nt], xb1, acc[nt], 0, 0, 0);
    }
    #pragma unroll
    for (int kb = 0; kb < 4; ++kb)
      #pragma unroll
      for (int nt = 0; nt < 7; ++nt)
        acc[nt] = __builtin_amdgcn_mfma_f32_16x16x32_f16(whh[kb][nt], hfrag[kb], acc[nt], 0, 0, 0);

    // h_{t+1} = tanh(preact); D regs -> next B-frag via per-lane cvt only
    #pragma unroll
    for (int nt = 0; nt < 7; ++nt)
      #pragma unroll
      for (int v = 0; v < 4; ++v)
        acc[nt][v] = tanh_fast(acc[nt][v]);

    #pragma unroll
    for (int kb = 0; kb < 4; ++kb) {
      half8 h;
      #pragma unroll
      for (int v = 0; v < 4; ++v) {
        h[v] = (_Float16)acc[2 * kb][v];
        h[4 + v] = (kb < 3) ? (_Float16)acc[2 * kb + 1][v] : (_Float16)0.0f;
      }
      hfrag[kb] = h;
    }

    s0 = p0; s1 = p1; s2 = p2; s3 = p3;
    p0 = q0; p1 = q1; p2 = q2; p3 = q3;
  }

  // ---- epilogue: out^T = fc_W * tanh(h_last)^T + fc_b
  #pragma unroll
  for (int nt = 0; nt < 7; ++nt)
    #pragma unroll
    for (int v = 0; v < 4; ++v)
      acc[nt][v] = tanh_fast(acc[nt][v]);
  #pragma unroll
  for (int kb = 0; kb < 4; ++kb) {
    half8 h;
    #pragma unroll
    for (int v = 0; v < 4; ++v) {
      h[v] = (_Float16)acc[2 * kb][v];
      h[4 + v] = (kb < 3) ? (_Float16)acc[2 * kb + 1][v] : (_Float16)0.0f;
    }
    hfrag[kb] = h;
  }

  half8 wfc[4][3];
  float4_t bfc[3];
  #pragma unroll
  for (int nt = 0; nt < 3; ++nt) {
    int nb = nt * 16 + 4 * g;
    float4_t bi = {0.f,0.f,0.f,0.f};
    if (nb + 3 < 40) bi = *(const float4_t*)(fc_b + nb);
    bfc[nt] = bi;

    int nrow = nt * 16 + c;
    bool rv = (nrow < 40);
    #pragma unroll
    for (int kb = 0; kb < 4; ++kb) {
      int clo = kb * 32 + 4 * g;
      int chi = clo + 16;
      float4_t f0 = {0.f,0.f,0.f,0.f}, f1 = {0.f,0.f,0.f,0.f};
      if (rv && clo + 3 < 100) f0 = *(const float4_t*)(fc_W + nrow * 100 + clo);
      if (rv && chi + 3 < 100) f1 = *(const float4_t*)(fc_W + nrow * 100 + chi);
      half8 h;
      #pragma unroll
      for (int j = 0; j < 4; ++j) { h[j] = (_Float16)f0[j]; h[4 + j] = (_Float16)f1[j]; }
      wfc[kb][nt] = h;
    }
  }

  float4_t oacc[3];
  #pragma unroll
  for (int nt = 0; nt < 3; ++nt) oacc[nt] = bfc[nt];
  #pragma unroll
  for (int kb = 0; kb < 4; ++kb)
    #pragma unroll
    for (int nt = 0; nt < 3; ++nt)
      oacc[nt] = __builtin_amdgcn_mfma_f32_16x16x32_f16(wfc[kb][nt], hfrag[kb], oacc[nt], 0, 0, 0);

  // store: lane (g,c) holds out[rowbase+c][n = 16nt+4g+v]
  #pragma unroll
  for (int nt = 0; nt < 3; ++nt)
    #pragma unroll
    for (int v = 0; v < 4; ++v) {
      int n = nt * 16 + 4 * g + v;
      if (n < 40)
        out[(size_t)(rowbase + c) * 40 + n] = oacc[nt][v];
    }
}

extern "C" void kernel_launch(void* const* d_in, const int* in_sizes, int n_in,
                              void* d_out, int out_size, void* d_ws, size_t ws_size,
                              hipStream_t stream) {
  const float* x    = (const float*)d_in[0];
  const float* W_ih = (const float*)d_in[1];
  const float* W_hh = (const float*)d_in[2];
  const float* b_ih = (const float*)d_in[3];
  const float* b_hh = (const float*)d_in[4];
  const float* fc_W = (const float*)d_in[5];
  const float* fc_b = (const float*)d_in[6];
  float* outp = (float*)d_out;

  int B = in_sizes[0] / 4096;      // 16384
  int grid = (B + 63) / 64;        // 64 batch rows per 4-wave block
  rnn_fused<<<grid, 256, 0, stream>>>(x, W_ih, W_hh, b_ih, b_hh, fc_W, fc_b, outp, B);
}